// Round 2
// baseline (293.680 us; speedup 1.0000x reference)
//
#include <hip/hip_runtime.h>

#define BB 8
#define NN 512
#define SS 96
#define HH 256
#define NHD 8
#define HDD 32
#define OUTD 4

// ws layout (floats)
#define Q_OFF   0
#define K_OFF   (4096*256)                 // 1048576
#define V_OFF   (K_OFF + 768*256)          // 1245184
#define CTX_OFF (V_OFF + 768*256)          // 1441792

// ---------------- Kernel 1: fused projections ----------------
// blocks 0..511: spatial (8 rows each)  -> q
// blocks 512..703: temporal (4 rows each) -> k, v
__global__ __launch_bounds__(256) void k_proj(
    const float* __restrict__ spatial, const float* __restrict__ temporal,
    const float* __restrict__ Ws, const float* __restrict__ bs,
    const float* __restrict__ Wt, const float* __restrict__ bt,
    const float* __restrict__ Win, const float* __restrict__ bin,
    float* __restrict__ q_out, float* __restrict__ k_out, float* __restrict__ v_out)
{
    __shared__ __align__(16) float IN[8][HH];
    __shared__ __align__(16) float MID[8][HH];
    const int tid = threadIdx.x;
    const int blk = blockIdx.x;
    const int rg = tid >> 7;      // 0/1 row group
    const int c  = tid & 127;     // column (pairs with c+128)

    if (blk < 512) {
        // ---------- spatial path: 8 rows ----------
        const int r0 = blk * 8;
        const float4* g4 = (const float4*)(spatial + (size_t)r0 * HH);
        for (int i = tid; i < 8 * HH / 4; i += 256) ((float4*)IN)[i] = g4[i];
        __syncthreads();

        // stage 1: sp = in @ Ws.T + bs  -> MID
        {
            float a0[4] = {}, a1[4] = {};
            const float4* w0 = (const float4*)(Ws + (size_t)c * HH);
            const float4* w1 = (const float4*)(Ws + (size_t)(c + 128) * HH);
            for (int kk = 0; kk < HH / 4; ++kk) {
                float4 wa = w0[kk], wb = w1[kk];
                #pragma unroll
                for (int r = 0; r < 4; ++r) {
                    float4 a = ((const float4*)IN[rg * 4 + r])[kk];
                    a0[r] += a.x * wa.x + a.y * wa.y + a.z * wa.z + a.w * wa.w;
                    a1[r] += a.x * wb.x + a.y * wb.y + a.z * wb.z + a.w * wb.w;
                }
            }
            float b0 = bs[c], b1 = bs[c + 128];
            #pragma unroll
            for (int r = 0; r < 4; ++r) {
                MID[rg * 4 + r][c]       = a0[r] + b0;
                MID[rg * 4 + r][c + 128] = a1[r] + b1;
            }
        }
        __syncthreads();
        // stage 2: q = sp @ Wq.T + bq  (Wq = Win[0:256]) -> global
        {
            float a0[4] = {}, a1[4] = {};
            const float4* w0 = (const float4*)(Win + (size_t)c * HH);
            const float4* w1 = (const float4*)(Win + (size_t)(c + 128) * HH);
            for (int kk = 0; kk < HH / 4; ++kk) {
                float4 wa = w0[kk], wb = w1[kk];
                #pragma unroll
                for (int r = 0; r < 4; ++r) {
                    float4 a = ((const float4*)MID[rg * 4 + r])[kk];
                    a0[r] += a.x * wa.x + a.y * wa.y + a.z * wa.z + a.w * wa.w;
                    a1[r] += a.x * wb.x + a.y * wb.y + a.z * wb.z + a.w * wb.w;
                }
            }
            float b0 = bin[c], b1 = bin[c + 128];
            #pragma unroll
            for (int r = 0; r < 4; ++r) {
                q_out[(size_t)(r0 + rg * 4 + r) * HH + c]       = a0[r] + b0;
                q_out[(size_t)(r0 + rg * 4 + r) * HH + c + 128] = a1[r] + b1;
            }
        }
    } else {
        // ---------- temporal path: 4 rows ----------
        const int r0 = (blk - 512) * 4;
        const float4* g4 = (const float4*)(temporal + (size_t)r0 * HH);
        for (int i = tid; i < 4 * HH / 4; i += 256) ((float4*)IN)[i] = g4[i];
        __syncthreads();

        // stage 1: tp = in @ Wt.T + bt -> MID (rows rg*2, rg*2+1)
        {
            float a0[2] = {}, a1[2] = {};
            const float4* w0 = (const float4*)(Wt + (size_t)c * HH);
            const float4* w1 = (const float4*)(Wt + (size_t)(c + 128) * HH);
            for (int kk = 0; kk < HH / 4; ++kk) {
                float4 wa = w0[kk], wb = w1[kk];
                #pragma unroll
                for (int r = 0; r < 2; ++r) {
                    float4 a = ((const float4*)IN[rg * 2 + r])[kk];
                    a0[r] += a.x * wa.x + a.y * wa.y + a.z * wa.z + a.w * wa.w;
                    a1[r] += a.x * wb.x + a.y * wb.y + a.z * wb.z + a.w * wb.w;
                }
            }
            float b0 = bt[c], b1 = bt[c + 128];
            #pragma unroll
            for (int r = 0; r < 2; ++r) {
                MID[rg * 2 + r][c]       = a0[r] + b0;
                MID[rg * 2 + r][c + 128] = a1[r] + b1;
            }
        }
        __syncthreads();
        // stage 2: k = tp @ Wk.T + bk ; v = tp @ Wv.T + bv
        {
            float ka0[2] = {}, ka1[2] = {}, va0[2] = {}, va1[2] = {};
            const float4* wk0 = (const float4*)(Win + (size_t)(HH + c) * HH);
            const float4* wk1 = (const float4*)(Win + (size_t)(HH + c + 128) * HH);
            const float4* wv0 = (const float4*)(Win + (size_t)(2 * HH + c) * HH);
            const float4* wv1 = (const float4*)(Win + (size_t)(2 * HH + c + 128) * HH);
            for (int kk = 0; kk < HH / 4; ++kk) {
                float4 wka = wk0[kk], wkb = wk1[kk], wva = wv0[kk], wvb = wv1[kk];
                #pragma unroll
                for (int r = 0; r < 2; ++r) {
                    float4 a = ((const float4*)MID[rg * 2 + r])[kk];
                    ka0[r] += a.x * wka.x + a.y * wka.y + a.z * wka.z + a.w * wka.w;
                    ka1[r] += a.x * wkb.x + a.y * wkb.y + a.z * wkb.z + a.w * wkb.w;
                    va0[r] += a.x * wva.x + a.y * wva.y + a.z * wva.z + a.w * wva.w;
                    va1[r] += a.x * wvb.x + a.y * wvb.y + a.z * wvb.z + a.w * wvb.w;
                }
            }
            float bk0 = bin[HH + c], bk1 = bin[HH + c + 128];
            float bv0 = bin[2 * HH + c], bv1 = bin[2 * HH + c + 128];
            #pragma unroll
            for (int r = 0; r < 2; ++r) {
                k_out[(size_t)(r0 + rg * 2 + r) * HH + c]       = ka0[r] + bk0;
                k_out[(size_t)(r0 + rg * 2 + r) * HH + c + 128] = ka1[r] + bk1;
                v_out[(size_t)(r0 + rg * 2 + r) * HH + c]       = va0[r] + bv0;
                v_out[(size_t)(r0 + rg * 2 + r) * HH + c + 128] = va1[r] + bv1;
            }
        }
    }
}

// ---------------- Kernel 2: attention ----------------
// grid B*NH*4 = 256 blocks x 256 threads; 128 rows/block, 2 threads/row (split S)
__global__ __launch_bounds__(256) void k_attn(
    const float* __restrict__ qg, const float* __restrict__ kg,
    const float* __restrict__ vg, float* __restrict__ ctxg)
{
    __shared__ __align__(16) float kl[SS][HDD];
    __shared__ __align__(16) float vl[SS][HDD];
    const int tid = threadIdx.x;
    const int blk = blockIdx.x;
    const int cc = blk & 3;
    const int h = (blk >> 2) & (NHD - 1);
    const int b = blk >> 5;

    for (int i = tid; i < SS * HDD / 4; i += 256) {
        int s = i >> 3, d4 = i & 7;
        ((float4*)kl[s])[d4] = *(const float4*)(kg + (size_t)(b * SS + s) * HH + h * HDD + d4 * 4);
        ((float4*)vl[s])[d4] = *(const float4*)(vg + (size_t)(b * SS + s) * HH + h * HDD + d4 * 4);
    }
    __syncthreads();

    const int hf = tid & 1;       // S-half
    const int r = tid >> 1;       // row within chunk
    const int n = cc * 128 + r;
    const float4* q4 = (const float4*)(qg + (size_t)(b * NN + n) * HH + h * HDD);
    float4 q[8];
    #pragma unroll
    for (int i = 0; i < 8; ++i) q[i] = q4[i];

    const float scale = 0.17677669529663687f;  // 1/sqrt(32)
    float sum = 0.f;
    float4 ctx[8] = {};
    const int s0 = hf * 48;
    for (int s = s0; s < s0 + 48; ++s) {
        float dot = 0.f;
        #pragma unroll
        for (int i = 0; i < 8; ++i) {
            float4 kk = ((const float4*)kl[s])[i];
            dot += q[i].x * kk.x + q[i].y * kk.y + q[i].z * kk.z + q[i].w * kk.w;
        }
        float p = __expf(dot * scale);   // no max-subtract: logits are O(1)
        sum += p;
        #pragma unroll
        for (int i = 0; i < 8; ++i) {
            float4 vv = ((const float4*)vl[s])[i];
            ctx[i].x += p * vv.x; ctx[i].y += p * vv.y;
            ctx[i].z += p * vv.z; ctx[i].w += p * vv.w;
        }
    }
    // combine the two S-halves (adjacent lanes)
    sum += __shfl_xor(sum, 1);
    #pragma unroll
    for (int i = 0; i < 8; ++i) {
        ctx[i].x += __shfl_xor(ctx[i].x, 1);
        ctx[i].y += __shfl_xor(ctx[i].y, 1);
        ctx[i].z += __shfl_xor(ctx[i].z, 1);
        ctx[i].w += __shfl_xor(ctx[i].w, 1);
    }
    float inv = 1.0f / sum;
    float4* o4 = (float4*)(ctxg + (size_t)(b * NN + n) * HH + h * HDD);
    #pragma unroll
    for (int i = 0; i < 4; ++i) {
        int idx = hf * 4 + i;
        o4[idx] = make_float4(ctx[idx].x * inv, ctx[idx].y * inv,
                              ctx[idx].z * inv, ctx[idx].w * inv);
    }
}

// ---------------- Kernel 3: head MLP + broadcast ----------------
// grid 512 blocks x 256 threads, 8 rows/block
__global__ __launch_bounds__(256) void k_head(
    const float* __restrict__ ctxg,
    const float* __restrict__ Wao, const float* __restrict__ bao,
    const float* __restrict__ W1, const float* __restrict__ b1,
    const float* __restrict__ Wo1, const float* __restrict__ bo1,
    const float* __restrict__ Wo2, const float* __restrict__ bo2,
    float* __restrict__ out)
{
    __shared__ __align__(16) float A[8][HH];
    __shared__ __align__(16) float Bf[8][HH];
    __shared__ __align__(16) float y[8][OUTD];
    const int tid = threadIdx.x;
    const int r0 = blockIdx.x * 8;  // row = b*N+n
    const int rg = tid >> 7;
    const int c  = tid & 127;

    const float4* g4 = (const float4*)(ctxg + (size_t)r0 * HH);
    for (int i = tid; i < 8 * HH / 4; i += 256) ((float4*)A)[i] = g4[i];
    __syncthreads();

    // stage 1: attended = ctx @ Wao.T + bao -> Bf
    {
        float a0[4] = {}, a1[4] = {};
        const float4* w0 = (const float4*)(Wao + (size_t)c * HH);
        const float4* w1 = (const float4*)(Wao + (size_t)(c + 128) * HH);
        for (int kk = 0; kk < HH / 4; ++kk) {
            float4 wa = w0[kk], wb = w1[kk];
            #pragma unroll
            for (int r = 0; r < 4; ++r) {
                float4 a = ((const float4*)A[rg * 4 + r])[kk];
                a0[r] += a.x * wa.x + a.y * wa.y + a.z * wa.z + a.w * wa.w;
                a1[r] += a.x * wb.x + a.y * wb.y + a.z * wb.z + a.w * wb.w;
            }
        }
        float b0 = bao[c], b1v = bao[c + 128];
        #pragma unroll
        for (int r = 0; r < 4; ++r) {
            Bf[rg * 4 + r][c]       = a0[r] + b0;
            Bf[rg * 4 + r][c + 128] = a1[r] + b1v;
        }
    }
    __syncthreads();
    // stage 2: fused = relu(attended @ W1.T + b1) -> A
    {
        float a0[4] = {}, a1[4] = {};
        const float4* w0 = (const float4*)(W1 + (size_t)c * HH);
        const float4* w1 = (const float4*)(W1 + (size_t)(c + 128) * HH);
        for (int kk = 0; kk < HH / 4; ++kk) {
            float4 wa = w0[kk], wb = w1[kk];
            #pragma unroll
            for (int r = 0; r < 4; ++r) {
                float4 a = ((const float4*)Bf[rg * 4 + r])[kk];
                a0[r] += a.x * wa.x + a.y * wa.y + a.z * wa.z + a.w * wa.w;
                a1[r] += a.x * wb.x + a.y * wb.y + a.z * wb.z + a.w * wb.w;
            }
        }
        float b0 = b1[c], b1v = b1[c + 128];
        #pragma unroll
        for (int r = 0; r < 4; ++r) {
            A[rg * 4 + r][c]       = fmaxf(a0[r] + b0, 0.f);
            A[rg * 4 + r][c + 128] = fmaxf(a1[r] + b1v, 0.f);
        }
    }
    __syncthreads();
    // stage 3: h2 = relu(fused @ Wo1.T + bo1) -> Bf[.][0..127]
    {
        float a0[4] = {};
        const float4* w0 = (const float4*)(Wo1 + (size_t)c * HH);
        for (int kk = 0; kk < HH / 4; ++kk) {
            float4 wa = w0[kk];
            #pragma unroll
            for (int r = 0; r < 4; ++r) {
                float4 a = ((const float4*)A[rg * 4 + r])[kk];
                a0[r] += a.x * wa.x + a.y * wa.y + a.z * wa.z + a.w * wa.w;
            }
        }
        float b0 = bo1[c];
        #pragma unroll
        for (int r = 0; r < 4; ++r)
            Bf[rg * 4 + r][c] = fmaxf(a0[r] + b0, 0.f);
    }
    __syncthreads();
    // stage 4: y = h2 @ Wo2.T + bo2  (8 rows x 4 outs, dots of 128)
    if (tid < 32) {
        int r = tid >> 2, o = tid & 3;
        float acc = 0.f;
        const float4* w4 = (const float4*)(Wo2 + (size_t)o * (HH / 2));
        for (int kk = 0; kk < (HH / 2) / 4; ++kk) {
            float4 w = w4[kk];
            float4 a = ((const float4*)Bf[r])[kk];
            acc += a.x * w.x + a.y * w.y + a.z * w.z + a.w * w.w;
        }
        y[r][o] = acc + bo2[o];
    }
    __syncthreads();
    // broadcast: out[b][s][nbase+r][:] = y[r]
    const int b = r0 >> 9;
    const int nbase = r0 & 511;
    for (int i = tid; i < 8 * SS; i += 256) {
        int s = i >> 3;
        int r = i & 7;
        *(float4*)(out + ((size_t)(b * SS + s) * NN + (nbase + r)) * OUTD) = *(const float4*)y[r];
    }
}

extern "C" void kernel_launch(void* const* d_in, const int* in_sizes, int n_in,
                              void* d_out, int out_size, void* d_ws, size_t ws_size,
                              hipStream_t stream) {
    const float* spatial  = (const float*)d_in[0];
    const float* temporal = (const float*)d_in[1];
    const float* Ws  = (const float*)d_in[2];
    const float* bs  = (const float*)d_in[3];
    const float* Wt  = (const float*)d_in[4];
    const float* bt  = (const float*)d_in[5];
    const float* Win = (const float*)d_in[6];
    const float* bin = (const float*)d_in[7];
    const float* Wao = (const float*)d_in[8];
    const float* bao = (const float*)d_in[9];
    const float* W1  = (const float*)d_in[10];
    const float* b1  = (const float*)d_in[11];
    const float* Wo1 = (const float*)d_in[12];
    const float* bo1 = (const float*)d_in[13];
    const float* Wo2 = (const float*)d_in[14];
    const float* bo2 = (const float*)d_in[15];
    float* out = (float*)d_out;
    float* ws  = (float*)d_ws;

    float* qbuf   = ws + Q_OFF;
    float* kbuf   = ws + K_OFF;
    float* vbuf   = ws + V_OFF;
    float* ctxbuf = ws + CTX_OFF;

    hipLaunchKernelGGL(k_proj, dim3(704), dim3(256), 0, stream,
                       spatial, temporal, Ws, bs, Wt, bt, Win, bin,
                       qbuf, kbuf, vbuf);
    hipLaunchKernelGGL(k_attn, dim3(BB * NHD * 4), dim3(256), 0, stream,
                       qbuf, kbuf, vbuf, ctxbuf);
    hipLaunchKernelGGL(k_head, dim3(BB * NN / 8), dim3(256), 0, stream,
                       ctxbuf, Wao, bao, W1, b1, Wo1, bo1, Wo2, bo2, out);
}